// Round 6
// baseline (36581.363 us; speedup 1.0000x reference)
//
#include <hip/hip_runtime.h>
#include <cstdint>
#include <cstddef>

#define B_ 32
#define T_ 2048
#define I_ 256
#define H_ 512

typedef float  f32x4  __attribute__((ext_vector_type(4)));
typedef __bf16 bf16x8 __attribute__((ext_vector_type(8)));
typedef unsigned long long u64;

__device__ __forceinline__ f32x4 MFMA(bf16x8 a, bf16x8 b, f32x4 c) {
    return __builtin_amdgcn_mfma_f32_16x16x32_bf16(a, b, c, 0, 0, 0);
}

__device__ __forceinline__ bf16x8 cvt8v(float4 a, float4 b) {
    bf16x8 r;
    r[0] = (__bf16)a.x; r[1] = (__bf16)a.y; r[2] = (__bf16)a.z; r[3] = (__bf16)a.w;
    r[4] = (__bf16)b.x; r[5] = (__bf16)b.y; r[6] = (__bf16)b.z; r[7] = (__bf16)b.w;
    return r;
}

// 2 persistent WGs x 512 threads. Wave (wg*8+wv) owns 32 h-columns, w_w slice
// in registers. Cross-WG exchange of h via IF-coherent (sc1) atomics + 16
// per-wave flags. No threadfence/wbl2; one __syncthreads per step (LDS stage).
__global__ __launch_bounds__(512) void rnn_scan2(
    const float* __restrict__ x, const __bf16* __restrict__ uwb,
    const float* __restrict__ u_b, const float* __restrict__ w_w,
    const float* __restrict__ w_b, __bf16* __restrict__ hs /* d_out as bf16 */,
    __bf16* __restrict__ hbuf /* ws: 2 x 32KB */, unsigned* __restrict__ flags)
{
    __shared__ char smem[65536];                 // 2 x 32KB ping-pong for h(t)
    const int tid = threadIdx.x, wv = tid >> 6, ln = tid & 63;
    const int l15 = ln & 15, lq = ln >> 4;
    const int wg  = blockIdx.x;                  // 0 or 1
    const int gwv = wg*8 + wv;                   // global wave id 0..15
    const int col0 = wg*256 + wv*32;             // this wave's 32 output cols
    const int ho0 = col0 + l15, ho1 = ho0 + 16;

    // persistent w_w B-fragments: [nt][kc], 128 VGPRs
    bf16x8 wf[2][16];
#pragma unroll
    for (int nt = 0; nt < 2; ++nt) {
        const float* wp = w_w + (size_t)(nt ? ho1 : ho0)*H_ + lq*8;
#pragma unroll
        for (int kc = 0; kc < 16; ++kc)
            wf[nt][kc] = cvt8v(*(const float4*)(wp + kc*32),
                               *(const float4*)(wp + kc*32 + 4));
    }
    const float bias0 = u_b[ho0] + w_b[ho0];
    const float bias1 = u_b[ho1] + w_b[ho1];

    f32x4 xacc[2][2];                            // xu(t), computed one step ahead
    auto xu_compute = [&](int t1) {
#pragma unroll
        for (int mt = 0; mt < 2; ++mt)
#pragma unroll
            for (int nt = 0; nt < 2; ++nt) xacc[mt][nt] = (f32x4){0.f,0.f,0.f,0.f};
#pragma unroll
        for (int kc = 0; kc < 8; ++kc) {
            const float* xp0 = x + ((size_t)l15*T_ + t1)*I_ + kc*32 + lq*8;
            const float* xp1 = x + ((size_t)(16 + l15)*T_ + t1)*I_ + kc*32 + lq*8;
            bf16x8 a0 = cvt8v(*(const float4*)xp0, *(const float4*)(xp0 + 4));
            bf16x8 a1 = cvt8v(*(const float4*)xp1, *(const float4*)(xp1 + 4));
            bf16x8 u0 = *(const bf16x8*)(uwb + (size_t)ho0*I_ + kc*32 + lq*8);
            bf16x8 u1 = *(const bf16x8*)(uwb + (size_t)ho1*I_ + kc*32 + lq*8);
            xacc[0][0] = MFMA(a0, u0, xacc[0][0]);
            xacc[0][1] = MFMA(a0, u1, xacc[0][1]);
            xacc[1][0] = MFMA(a1, u0, xacc[1][0]);
            xacc[1][1] = MFMA(a1, u1, xacc[1][1]);
        }
    };
    xu_compute(0);                               // xu(0) prologue

    for (int t = 0; t < T_; ++t) {
        // 1. acquire: all 16 wave-flags >= t  (h(t) complete at coherent point)
        if (t) {
            const unsigned* fp = flags + (l15 << 4);   // lane l15 polls flag l15
            for (;;) {
                unsigned f = __hip_atomic_load(fp, __ATOMIC_RELAXED,
                                               __HIP_MEMORY_SCOPE_AGENT);
                if (__all(f >= (unsigned)t)) break;
            }
        }
        // 2. cooperative coherent load of h(t) (32KB) -> swizzled LDS
        const char* curg = (const char*)hbuf + (t & 1)*32768;
        char* sbase = smem + (t & 1)*32768;
        {
            const u64* gsrc = (const u64*)(curg + (wv*4096 + ln*64));
            u64 q[8];
#pragma unroll
            for (int j = 0; j < 8; ++j)
                q[j] = __hip_atomic_load(gsrc + j, __ATOMIC_RELAXED,
                                         __HIP_MEMORY_SCOPE_AGENT);
            const unsigned baseb = (unsigned)(wv*4096 + ln*64);
            const unsigned swz   = ((baseb >> 10) & 7) << 4;   // row-XOR swizzle
#pragma unroll
            for (int j = 0; j < 4; ++j) {
                uint4 w4 = make_uint4((unsigned)q[2*j], (unsigned)(q[2*j] >> 32),
                                      (unsigned)q[2*j+1], (unsigned)(q[2*j+1] >> 32));
                *(uint4*)(sbase + ((baseb + j*16) ^ swz)) = w4;
            }
        }
        __syncthreads();
        // 3. h(t) @ W^T : 64 MFMAs from LDS (swizzled reads, conflict-free)
        f32x4 acc[2][2] = {};
        const unsigned swz0 = (unsigned)((l15 & 7) << 4);      // rows l15, l15+16
        const unsigned b0 = (unsigned)(l15*1024 + lq*16);
        const unsigned b1 = b0 + 16*1024;
#pragma unroll
        for (int kc = 0; kc < 16; ++kc) {
            bf16x8 a0 = *(const bf16x8*)(sbase + ((b0 + kc*64) ^ swz0));
            bf16x8 a1 = *(const bf16x8*)(sbase + ((b1 + kc*64) ^ swz0));
            acc[0][0] = MFMA(a0, wf[0][kc], acc[0][0]);
            acc[0][1] = MFMA(a0, wf[1][kc], acc[0][1]);
            acc[1][0] = MFMA(a1, wf[0][kc], acc[1][0]);
            acc[1][1] = MFMA(a1, wf[1][kc], acc[1][1]);
        }
        // 4. v = hW + xu + bias; tanh; write-through stores of h(t+1); hs plain
        __bf16* nxtg = hbuf + ((t + 1) & 1)*(B_*H_);
#pragma unroll
        for (int mt = 0; mt < 2; ++mt)
#pragma unroll
        for (int nt = 0; nt < 2; ++nt) {
            const int col = nt ? ho1 : ho0;
            const float bs = nt ? bias1 : bias0;
#pragma unroll
            for (int r = 0; r < 4; ++r) {
                float v = acc[mt][nt][r] + xacc[mt][nt][r] + bs;
                float e = __expf(2.f * v);
                float h = 1.f - 2.f/(e + 1.f);             // tanh, saturates
                __bf16 hb = (__bf16)h;
                unsigned short us; __builtin_memcpy(&us, &hb, 2);
                const int brow = mt*16 + lq*4 + r;
                __hip_atomic_store((unsigned short*)(nxtg + (size_t)brow*H_ + col),
                                   us, __ATOMIC_RELAXED, __HIP_MEMORY_SCOPE_AGENT);
                hs[((size_t)brow*T_ + t)*H_ + col] = hb;   // plain, L2-dirty ok
            }
        }
        // 5. release: all this wave's stores acked at their destination, then flag
        asm volatile("s_waitcnt vmcnt(0)" ::: "memory");
        if (ln == 0)
            __hip_atomic_store(flags + (gwv << 4), (unsigned)(t + 1),
                               __ATOMIC_RELAXED, __HIP_MEMORY_SCOPE_AGENT);
        // 6. slack (hidden under partner WG's turnaround): xu(t+1)
        if (t + 1 < T_) xu_compute(t + 1);
    }
}

// convert u_w and o_w to bf16 (ws staging)
__global__ void cvt_wb(const float* __restrict__ uw, const float* __restrict__ ow,
                       __bf16* __restrict__ uwb, __bf16* __restrict__ owb) {
    int i = blockIdx.x * blockDim.x + threadIdx.x;
    if (i < H_*I_) uwb[i] = (__bf16)uw[i];
    else { int j = i - H_*I_; if (j < I_*H_) owb[j] = (__bf16)ow[j]; }
}

// Epilogue: out[bt,i] = sigmoid(hs[bt,:] @ o_w[i,:]^T + o_b[i]); in-place over hs.
__global__ __launch_bounds__(256, 1) void out_proj(
    const __bf16* hs, const __bf16* __restrict__ owb,
    const float* __restrict__ o_b, float* out)
{
    const int tid = threadIdx.x, wv = tid >> 6, ln = tid & 63;
    const int l15 = ln & 15, lq = ln >> 4;
    const size_t m0 = (size_t)blockIdx.x * 32;
    const __bf16* a0p = hs + (m0 + l15)*H_ + lq*8;
    const __bf16* a1p = a0p + (size_t)16*H_;
    f32x4 acc[2][4] = {};
#pragma unroll
    for (int kc = 0; kc < 16; ++kc) {
        bf16x8 a0 = *(const bf16x8*)(a0p + kc*32);
        bf16x8 a1 = *(const bf16x8*)(a1p + kc*32);
#pragma unroll
        for (int nt = 0; nt < 4; ++nt) {
            const __bf16* bp = owb + (size_t)(wv*64 + nt*16 + l15)*H_ + kc*32 + lq*8;
            bf16x8 b = *(const bf16x8*)bp;
            acc[0][nt] = MFMA(a0, b, acc[0][nt]);
            acc[1][nt] = MFMA(a1, b, acc[1][nt]);
        }
    }
    __syncthreads();   // all waves' A-loads complete before any wave overwrites hs
#pragma unroll
    for (int nt = 0; nt < 4; ++nt) {
        const int col = wv*64 + nt*16 + l15;
        const float ob = o_b[col];
#pragma unroll
        for (int mt = 0; mt < 2; ++mt) {
#pragma unroll
            for (int r = 0; r < 4; ++r) {
                const size_t row = m0 + mt*16 + lq*4 + r;
                float v = acc[mt][nt][r] + ob;
                out[row*I_ + col] = 1.f/(1.f + __expf(-v));
            }
        }
    }
}

extern "C" void kernel_launch(void* const* d_in, const int* in_sizes, int n_in,
                              void* d_out, int out_size, void* d_ws, size_t ws_size,
                              hipStream_t stream)
{
    const float* x   = (const float*)d_in[0];
    const float* u_w = (const float*)d_in[1];
    const float* u_b = (const float*)d_in[2];
    const float* w_w = (const float*)d_in[3];
    const float* w_b = (const float*)d_in[4];
    const float* o_w = (const float*)d_in[5];
    const float* o_b = (const float*)d_in[6];

    char* ws = (char*)d_ws;
    __bf16*   hbuf  = (__bf16*)ws;                  // 2 x 32 KB @ 0
    unsigned* flags = (unsigned*)(ws + 65536);      // 16 x 64 B   @ 64 KB
    __bf16*   uwb   = (__bf16*)(ws + 131072);       // 256 KB      @ 128 KB
    __bf16*   owb   = (__bf16*)(ws + 393216);       // 256 KB      @ 384 KB

    // re-arm: zero h(0) ping-pong + flags every launch (ws poisoned each call)
    hipMemsetAsync(d_ws, 0, 66560, stream);
    cvt_wb<<<dim3((2*H_*I_)/256), dim3(256), 0, stream>>>(u_w, o_w, uwb, owb);
    rnn_scan2<<<dim3(2), dim3(512), 0, stream>>>(x, uwb, u_b, w_w, w_b,
                                                 (__bf16*)d_out, hbuf, flags);
    out_proj<<<dim3((B_*T_)/32), dim3(256), 0, stream>>>((const __bf16*)d_out, owb,
                                                         o_b, (float*)d_out);
}

// Round 8
// 23405.614 us; speedup vs baseline: 1.5629x; 1.5629x over previous
//
#include <hip/hip_runtime.h>
#include <cstdint>
#include <cstddef>

#define B_ 32
#define T_ 2048
#define I_ 256
#define H_ 512
#define TEAM 16
#define NWG 128

typedef float  f32x4  __attribute__((ext_vector_type(4)));
typedef __bf16 bf16x8 __attribute__((ext_vector_type(8)));
typedef unsigned int u32x4 __attribute__((ext_vector_type(4)));

__device__ __forceinline__ f32x4 MFMA(bf16x8 a, bf16x8 b, f32x4 c) {
    return __builtin_amdgcn_mfma_f32_16x16x32_bf16(a, b, c, 0, 0, 0);
}

__device__ __forceinline__ bf16x8 cvt8v(float4 a, float4 b) {
    bf16x8 r;
    r[0] = (__bf16)a.x; r[1] = (__bf16)a.y; r[2] = (__bf16)a.z; r[3] = (__bf16)a.w;
    r[4] = (__bf16)b.x; r[5] = (__bf16)b.y; r[6] = (__bf16)b.z; r[7] = (__bf16)b.w;
    return r;
}

// L1-bypassing 16B load: reads the XCD-shared L2 (intra-XCD coherence point).
__device__ __forceinline__ u32x4 ld16_sc0(const void* p) {
    u32x4 r;
    asm volatile("global_load_dwordx4 %0, %1, off sc0" : "=v"(r) : "v"(p));
    return r;
}

#define VWAIT(N) do { asm volatile("s_waitcnt vmcnt(" #N ")" ::: "memory"); \
                      __builtin_amdgcn_sched_barrier(0); } while (0)

template<int Q>
__device__ __forceinline__ void issueQ(const __bf16* cur, int l15, int lq,
                                       u32x4 (&buf)[2][4]) {
#pragma unroll
    for (int mt = 0; mt < 2; ++mt)
#pragma unroll
        for (int k2 = 0; k2 < 4; ++k2)
            buf[mt][k2] = ld16_sc0(cur + (size_t)(mt*16 + l15)*H_ +
                                   (Q*4 + k2)*32 + lq*8);
}

template<int Q>
__device__ __forceinline__ void mfmaQ(const u32x4 (&buf)[2][4],
                                      const bf16x8 (&wf)[2][16],
                                      f32x4 (&acc)[2][2]) {
#pragma unroll
    for (int k2 = 0; k2 < 4; ++k2)
#pragma unroll
        for (int mt = 0; mt < 2; ++mt) {
            bf16x8 a_ = __builtin_bit_cast(bf16x8, buf[mt][k2]);
            acc[mt][0] = MFMA(a_, wf[0][Q*4 + k2], acc[mt][0]);
            acc[mt][1] = MFMA(a_, wf[1][Q*4 + k2], acc[mt][1]);
        }
}

// 128 single-wave WGs; the first XCD to gather 16 waves runs the scan with
// all exchange through its own (coherent) L2. Everyone else exits.
__global__ __launch_bounds__(64, 1) void rnn_scan3(
    const float* __restrict__ x, const __bf16* __restrict__ uwb,
    const float* __restrict__ u_b, const float* __restrict__ w_w,
    const float* __restrict__ w_b, __bf16* __restrict__ hs /* d_out as bf16 */,
    __bf16* __restrict__ hbuf, unsigned* __restrict__ flags,
    unsigned* __restrict__ claim, unsigned* __restrict__ winner)
{
    const int ln = threadIdx.x;
    const int l15 = ln & 15, lq = ln >> 4;

    // ---- team formation ----
    const int xcc = __builtin_amdgcn_s_getreg(63508) & 7;  // hwreg(HW_REG_XCC_ID=20,0,32)
    int rank = 0;
    if (ln == 0) rank = (int)atomicAdd(&claim[xcc], 1u);   // device-scope
    rank = __shfl(rank, 0);
    if (rank == TEAM - 1 && ln == 0) atomicCAS(winner, 0u, (unsigned)(xcc + 1));
    if (rank >= TEAM) return;
    unsigned win;
    do { win = __hip_atomic_load(winner, __ATOMIC_ACQUIRE,
                                 __HIP_MEMORY_SCOPE_AGENT); } while (win == 0);
    if (win != (unsigned)(xcc + 1)) return;

    const int role = rank;            // 0..15
    const int c0 = role * 32;         // this wave's 32 h-columns

    // ---- persistent state ----
    bf16x8 wf[2][16];                 // w_w B-fragments (128 VGPRs)
#pragma unroll
    for (int nt = 0; nt < 2; ++nt) {
        const float* wp = w_w + (size_t)(c0 + nt*16 + l15)*H_ + lq*8;
#pragma unroll
        for (int kc = 0; kc < 16; ++kc)
            wf[nt][kc] = cvt8v(*(const float4*)(wp + kc*32),
                               *(const float4*)(wp + kc*32 + 4));
    }
    float bias[2];
    bias[0] = u_b[c0 + l15]      + w_b[c0 + l15];
    bias[1] = u_b[c0 + 16 + l15] + w_b[c0 + 16 + l15];

    f32x4 xacc[2][2];
    auto xu_compute = [&](int tt) {
#pragma unroll
        for (int mt = 0; mt < 2; ++mt)
#pragma unroll
            for (int nt = 0; nt < 2; ++nt) xacc[mt][nt] = (f32x4){0.f,0.f,0.f,0.f};
#pragma unroll
        for (int kc = 0; kc < 8; ++kc) {
            const float* xp0 = x + ((size_t)l15*T_ + tt)*I_ + kc*32 + lq*8;
            const float* xp1 = xp0 + (size_t)16*T_*I_;
            bf16x8 a0 = cvt8v(*(const float4*)xp0, *(const float4*)(xp0 + 4));
            bf16x8 a1 = cvt8v(*(const float4*)xp1, *(const float4*)(xp1 + 4));
            bf16x8 u0 = *(const bf16x8*)(uwb + (size_t)(c0 + l15)*I_ + kc*32 + lq*8);
            bf16x8 u1 = *(const bf16x8*)(uwb + (size_t)(c0 + 16 + l15)*I_ + kc*32 + lq*8);
            xacc[0][0] = MFMA(a0, u0, xacc[0][0]);
            xacc[0][1] = MFMA(a0, u1, xacc[0][1]);
            xacc[1][0] = MFMA(a1, u0, xacc[1][0]);
            xacc[1][1] = MFMA(a1, u1, xacc[1][1]);
        }
    };
    xu_compute(0);

    const unsigned* fp = flags + ((ln & 15) << 4);   // poll addr (64B-spaced flags)

    for (int t = 0; t < T_; ++t) {
        // 1. acquire: all 16 wave-flags >= t  (sc0 = read shared L2, skip stale L1)
        if (t) {
            unsigned f;
            do {
                asm volatile("global_load_dword %0, %1, off sc0\n\t"
                             "s_waitcnt vmcnt(0)"
                             : "=v"(f) : "v"(fp) : "memory");
            } while (!__all(f >= (unsigned)t));
        }
        // 2. h(t) @ W^T: pipelined sc0 A-loads (4 batches x 8) + 64 MFMAs
        const __bf16* cur = hbuf + (size_t)(t & 1)*(B_*H_);
        u32x4 A0[2][4], A1[2][4];
        f32x4 acc[2][2] = {};
        issueQ<0>(cur, l15, lq, A0);
        issueQ<1>(cur, l15, lq, A1);
        VWAIT(8);  mfmaQ<0>(A0, wf, acc);
        issueQ<2>(cur, l15, lq, A0);
        VWAIT(8);  mfmaQ<1>(A1, wf, acc);
        issueQ<3>(cur, l15, lq, A1);
        VWAIT(8);  mfmaQ<2>(A0, wf, acc);
        VWAIT(0);  mfmaQ<3>(A1, wf, acc);
        // 3. v = hW + xu + bias; tanh; store h(t+1) slice (plain -> shared L2)
        __bf16* nxt = hbuf + (size_t)((t + 1) & 1)*(B_*H_);
        __bf16 hv[2][2][4];
#pragma unroll
        for (int mt = 0; mt < 2; ++mt)
#pragma unroll
        for (int nt = 0; nt < 2; ++nt)
#pragma unroll
        for (int r = 0; r < 4; ++r) {
            float v = acc[mt][nt][r] + xacc[mt][nt][r] + bias[nt];
            float e = __expf(2.f * v);
            float h = 1.f - 2.f/(e + 1.f);          // tanh, saturates cleanly
            __bf16 hb = (__bf16)h;
            hv[mt][nt][r] = hb;
            nxt[(size_t)(mt*16 + lq*4 + r)*H_ + c0 + nt*16 + l15] = hb;
        }
        // 4. release: h-stores acked at L2, then publish flag
        VWAIT(0);
        if (ln == 0) flags[role << 4] = (unsigned)(t + 1);
        __builtin_amdgcn_sched_barrier(0);
        // 5. slack (hidden under partners' turnaround): hs write + xu(t+1)
#pragma unroll
        for (int mt = 0; mt < 2; ++mt)
#pragma unroll
        for (int nt = 0; nt < 2; ++nt)
#pragma unroll
        for (int r = 0; r < 4; ++r)
            hs[((size_t)(mt*16 + lq*4 + r)*T_ + t)*H_ + c0 + nt*16 + l15] = hv[mt][nt][r];
        if (t + 1 < T_) xu_compute(t + 1);
    }
}

// convert u_w and o_w to bf16 (ws staging)
__global__ void cvt_wb(const float* __restrict__ uw, const float* __restrict__ ow,
                       __bf16* __restrict__ uwb, __bf16* __restrict__ owb) {
    int i = blockIdx.x * blockDim.x + threadIdx.x;
    if (i < H_*I_) uwb[i] = (__bf16)uw[i];
    else { int j = i - H_*I_; if (j < I_*H_) owb[j] = (__bf16)ow[j]; }
}

// Epilogue: out[bt,i] = sigmoid(hs[bt,:] @ o_w[i,:]^T + o_b[i]); in-place over hs.
// __syncthreads between MFMA loads and stores: read-before-overwrite across waves.
__global__ __launch_bounds__(256, 1) void out_proj(
    const __bf16* hs, const __bf16* __restrict__ owb,
    const float* __restrict__ o_b, float* out)
{
    const int tid = threadIdx.x, wv = tid >> 6, ln = tid & 63;
    const int l15 = ln & 15, lq = ln >> 4;
    const size_t m0 = (size_t)blockIdx.x * 32;
    const __bf16* a0p = hs + (m0 + l15)*H_ + lq*8;
    const __bf16* a1p = a0p + (size_t)16*H_;
    f32x4 acc[2][4] = {};
#pragma unroll
    for (int kc = 0; kc < 16; ++kc) {
        bf16x8 a0 = *(const bf16x8*)(a0p + kc*32);
        bf16x8 a1 = *(const bf16x8*)(a1p + kc*32);
#pragma unroll
        for (int nt = 0; nt < 4; ++nt) {
            const __bf16* bp = owb + (size_t)(wv*64 + nt*16 + l15)*H_ + kc*32 + lq*8;
            bf16x8 b = *(const bf16x8*)bp;
            acc[0][nt] = MFMA(a0, b, acc[0][nt]);
            acc[1][nt] = MFMA(a1, b, acc[1][nt]);
        }
    }
    __syncthreads();
#pragma unroll
    for (int nt = 0; nt < 4; ++nt) {
        const int col = wv*64 + nt*16 + l15;
        const float ob = o_b[col];
#pragma unroll
        for (int mt = 0; mt < 2; ++mt) {
#pragma unroll
            for (int r = 0; r < 4; ++r) {
                const size_t row = m0 + mt*16 + lq*4 + r;
                float v = acc[mt][nt][r] + ob;
                out[row*I_ + col] = 1.f/(1.f + __expf(-v));
            }
        }
    }
}

extern "C" void kernel_launch(void* const* d_in, const int* in_sizes, int n_in,
                              void* d_out, int out_size, void* d_ws, size_t ws_size,
                              hipStream_t stream)
{
    const float* x   = (const float*)d_in[0];
    const float* u_w = (const float*)d_in[1];
    const float* u_b = (const float*)d_in[2];
    const float* w_w = (const float*)d_in[3];
    const float* w_b = (const float*)d_in[4];
    const float* o_w = (const float*)d_in[5];
    const float* o_b = (const float*)d_in[6];

    char* ws = (char*)d_ws;
    __bf16*   hbuf   = (__bf16*)ws;                  // 2 x 32 KB      @ 0
    unsigned* flags  = (unsigned*)(ws + 65536);      // 16 x 64 B      @ 64 KB
    unsigned* claim  = (unsigned*)(ws + 66560);      // 8 x 4 B        @ 65 KB
    unsigned* winner = (unsigned*)(ws + 66592);      // 4 B
    __bf16*   uwb    = (__bf16*)(ws + 131072);       // 256 KB         @ 128 KB
    __bf16*   owb    = (__bf16*)(ws + 393216);       // 256 KB         @ 384 KB

    // re-arm: zero hbuf + flags + claim + winner every launch
    hipMemsetAsync(d_ws, 0, 66600, stream);
    cvt_wb<<<dim3((2*H_*I_)/256), dim3(256), 0, stream>>>(u_w, o_w, uwb, owb);
    rnn_scan3<<<dim3(NWG), dim3(64), 0, stream>>>(x, uwb, u_b, w_w, w_b,
                                                  (__bf16*)d_out, hbuf, flags,
                                                  claim, winner);
    out_proj<<<dim3((B_*T_)/32), dim3(256), 0, stream>>>((const __bf16*)d_out, owb,
                                                         o_b, (float*)d_out);
}